// Round 4
// baseline (179.835 us; speedup 1.0000x reference)
//
#include <hip/hip_runtime.h>
#include <math.h>

typedef unsigned long long ull;
typedef __attribute__((ext_vector_type(8))) short bf16x8;
typedef __attribute__((ext_vector_type(4))) float f32x4;

#define PPB   16384
#define NB    4
#define TOPK  4096
#define NPTS  65536
#define NBUCK 16384
#define BSCALE 2048.0f   // linear monotone bucketing: ~1-3 pts/bucket (scores plateau near max)

// workspace layout (bytes)
#define SRAW_OFF  0u          // N f32 (256 KB)
#define ST_OFF    262144u     // 64 words stats
#define SUF_OFF   262400u     // 4*16384 u32 (256 KB)
#define CAND_OFF  524544u     // 4*16384 u64 (512 KB)
#define FIDX_OFF  1048832u    // 16384 i32
#define SW_OFF    1114368u    // 16384 f32
#define W2SH_OFF  1179904u    // 256*256 bf16 chunk-swizzled image (hi)
#define W2SL_OFF  1310976u    // (lo)
#define WP1H_OFF  1442048u    // wp1^T image (hi)
#define WP1L_OFF  1573120u    // (lo)   end 1704192

// stats word indices
#define SI_SUMS  0
#define SI_SUMS2 1
#define SI_ESEL  12  // ..15 per-batch sum exp (selected)

union frag_u { unsigned d[4]; bf16x8 v; uint4 q; };

__device__ __forceinline__ unsigned short f2bf(float f) {
  unsigned u = __float_as_uint(f);
  unsigned r = 0x7FFFu + ((u >> 16) & 1u);   // RTNE
  return (unsigned short)((u + r) >> 16);
}
__device__ __forceinline__ float bf2f(unsigned short h) {
  return __uint_as_float((unsigned)h << 16);
}
__device__ __forceinline__ unsigned sc2bucket(float sc) {
  unsigned b = (unsigned)(sc * BSCALE);      // monotone in sc (sc >= 0)
  return b > NBUCK - 1u ? NBUCK - 1u : b;
}

// ---- cooperative A-fragment builders: one lane builds one 8-element K-granule
// (granule g2 of chunk, row `row`) into the swizzled LDS A image.
// hi/lo truncation-split variant (bit-identical to round-0 in-register path).
__device__ __forceinline__ void build_a_hl(
    int kb, int g2, int row, float4 pv,
    const float* __restrict__ w1_l, const float* __restrict__ b1_l,
    short* dh, short* dl)
{
  float wk0[8], wk1[8], wk2[8], wk3[8], bk[8];
  *(float4*)&wk0[0] = *(const float4*)&w1_l[kb];
  *(float4*)&wk0[4] = *(const float4*)&w1_l[kb + 4];
  *(float4*)&wk1[0] = *(const float4*)&w1_l[256 + kb];
  *(float4*)&wk1[4] = *(const float4*)&w1_l[256 + kb + 4];
  *(float4*)&wk2[0] = *(const float4*)&w1_l[512 + kb];
  *(float4*)&wk2[4] = *(const float4*)&w1_l[512 + kb + 4];
  *(float4*)&wk3[0] = *(const float4*)&w1_l[768 + kb];
  *(float4*)&wk3[4] = *(const float4*)&w1_l[768 + kb + 4];
  *(float4*)&bk[0] = *(const float4*)&b1_l[kb];
  *(float4*)&bk[4] = *(const float4*)&b1_l[kb + 4];
  frag_u uh, ul;
#pragma unroll
  for (int jp = 0; jp < 4; ++jp) {
    int j0 = 2 * jp, j1 = 2 * jp + 1;
    float h0 = fmaf(pv.w, wk3[j0], fmaf(pv.z, wk2[j0],
               fmaf(pv.y, wk1[j0], fmaf(pv.x, wk0[j0], bk[j0]))));
    float h1 = fmaf(pv.w, wk3[j1], fmaf(pv.z, wk2[j1],
               fmaf(pv.y, wk1[j1], fmaf(pv.x, wk0[j1], bk[j1]))));
    h0 = fmaxf(h0, 0.f); h1 = fmaxf(h1, 0.f);
    unsigned u0 = __float_as_uint(h0), u1 = __float_as_uint(h1);
    uh.d[jp] = (u0 >> 16) | (u1 & 0xFFFF0000u);
    float r0 = h0 - __uint_as_float(u0 & 0xFFFF0000u);
    float r1 = h1 - __uint_as_float(u1 & 0xFFFF0000u);
    ul.d[jp] = (__float_as_uint(r0) >> 16) | (__float_as_uint(r1) & 0xFFFF0000u);
  }
  const int wo = row * 32 + ((g2 ^ ((row >> 1) & 3)) << 3);
  *(uint4*)&dh[wo] = uh.q;
  *(uint4*)&dl[wo] = ul.q;
}

// hi-only RTNE variant (k_proc GEMM1, bit-identical to round-0 path)
__device__ __forceinline__ void build_a_h(
    int kb, int g2, int row, float4 pv,
    const float* __restrict__ w1_l, const float* __restrict__ b1_l,
    short* dh)
{
  float wk0[8], wk1[8], wk2[8], wk3[8], bk[8];
  *(float4*)&wk0[0] = *(const float4*)&w1_l[kb];
  *(float4*)&wk0[4] = *(const float4*)&w1_l[kb + 4];
  *(float4*)&wk1[0] = *(const float4*)&w1_l[256 + kb];
  *(float4*)&wk1[4] = *(const float4*)&w1_l[256 + kb + 4];
  *(float4*)&wk2[0] = *(const float4*)&w1_l[512 + kb];
  *(float4*)&wk2[4] = *(const float4*)&w1_l[512 + kb + 4];
  *(float4*)&wk3[0] = *(const float4*)&w1_l[768 + kb];
  *(float4*)&wk3[4] = *(const float4*)&w1_l[768 + kb + 4];
  *(float4*)&bk[0] = *(const float4*)&b1_l[kb];
  *(float4*)&bk[4] = *(const float4*)&b1_l[kb + 4];
  frag_u uh;
#pragma unroll
  for (int jp = 0; jp < 4; ++jp) {
    int j0 = 2 * jp, j1 = 2 * jp + 1;
    float h0 = fmaf(pv.w, wk3[j0], fmaf(pv.z, wk2[j0],
               fmaf(pv.y, wk1[j0], fmaf(pv.x, wk0[j0], bk[j0]))));
    float h1 = fmaf(pv.w, wk3[j1], fmaf(pv.z, wk2[j1],
               fmaf(pv.y, wk1[j1], fmaf(pv.x, wk0[j1], bk[j1]))));
    uh.d[jp] = (unsigned)f2bf(fmaxf(h0, 0.f)) |
               ((unsigned)f2bf(fmaxf(h1, 0.f)) << 16);
  }
  const int wo = row * 32 + ((g2 ^ ((row >> 1) & 3)) << 3);
  *(uint4*)&dh[wo] = uh.q;
}

// ---------------- prep: images (coalesced) + stats zeroing ----------------
__global__ __launch_bounds__(256) void k_prep(
    const float* __restrict__ w2, const float* __restrict__ wp1,
    unsigned short* __restrict__ w2h, unsigned short* __restrict__ w2l,
    unsigned short* __restrict__ p1h, unsigned short* __restrict__ p1l,
    float* __restrict__ stats)
{
  const int t = threadIdx.x, bx = blockIdx.x;
  if (bx >= 16) {
    if (t < 64) stats[t] = 0.f;
    return;
  }
  __shared__ unsigned short lh[8192], ll[8192];
  const int c = bx & 7;
  const float* src = (bx >= 8) ? wp1 : w2;
  unsigned short* dh = (bx >= 8) ? p1h : w2h;
  unsigned short* dl = (bx >= 8) ? p1l : w2l;
  const int sw = (t >> 1) & 3;
#pragma unroll
  for (int kk = 0; kk < 32; ++kk) {
    float v = src[(c * 32 + kk) * 256 + t];      // coalesced 256-wide
    unsigned short h = f2bf(v);
    int q = kk >> 3, kof = kk & 7;
    int off = t * 32 + ((q ^ sw) << 3) + kof;
    lh[off] = h;
    ll[off] = f2bf(v - bf2f(h));
  }
  __syncthreads();
#pragma unroll
  for (int u = 0; u < 4; ++u) {
    ((uint4*)&dh[c * 8192])[u * 256 + t] = ((const uint4*)lh)[u * 256 + t];
    ((uint4*)&dl[c * 8192])[u * 256 + t] = ((const uint4*)ll)[u * 256 + t];
  }
}

// ---------------- K1: score-only point MLP, M=64/block, 8 waves ----------------
// v5: ZERO VMEM in the K-loop. The wave's whole B slice (32 cols x 256 K,
// hi+lo = 32 KB = 128 VGPR) is loaded up front -- the build phase + barrier
// hide the L2 latency once, instead of per-chunk exposure (the ~46us invariant
// across v0-v4 matches ~3400cy/chunk of exposed VMEM wait). A fragments are
// register-double-buffered one chunk ahead (counted lgkmcnt by compiler).
// (512,2): 256-VGPR budget for the ~236-reg peak; occupancy unchanged vs
// measured (8 waves/CU).
__global__ __launch_bounds__(512, 2) void k_mlp(
    const float4* __restrict__ pts4, const float* __restrict__ w1,
    const float* __restrict__ b1,
    const unsigned short* __restrict__ w2h, const unsigned short* __restrict__ w2l,
    const float* __restrict__ b2, const float* __restrict__ wsv,
    const float* __restrict__ bs,
    float* __restrict__ s_raw, float* stats_f)
{
  __shared__ float w1_l[1024];
  __shared__ float b1_l[256];
  __shared__ float pts_l[256];
  __shared__ float spart[512];                   // 64 rows x 8 waves
  __shared__ __align__(16) short Ahh[8][2048];   // 32 KB: A hi, full 64x256 swizzled
  __shared__ __align__(16) short All[8][2048];   // 32 KB: A lo

  const int t = threadIdx.x;
  const int m0 = blockIdx.x * 64;
  const int wv = t >> 6, lane = t & 63, g = lane >> 4, c0 = lane & 15;

  int boff[2];
#pragma unroll
  for (int nt = 0; nt < 2; ++nt) {
    int n = wv * 32 + nt * 16 + c0;
    boff[nt] = n * 32 + ((g ^ ((n >> 1) & 3)) << 3);
  }

  // load the wave's ENTIRE B slice into registers (latency hidden by
  // LDS staging + build phase + barrier below)
  bf16x8 rbh[8][2], rbl[8][2];
#pragma unroll
  for (int c = 0; c < 8; ++c)
#pragma unroll
    for (int nt = 0; nt < 2; ++nt) {
      rbh[c][nt] = *(const bf16x8*)&w2h[c * 8192 + boff[nt]];
      rbl[c][nt] = *(const bf16x8*)&w2l[c * 8192 + boff[nt]];
    }

#pragma unroll
  for (int i = 0; i < 2; ++i) w1_l[i * 512 + t] = w1[i * 512 + t];
  if (t < 256) b1_l[t] = b1[t];
  if (t < 64) ((float4*)pts_l)[t] = pts4[m0 + t];

  f32x4 acc[4][2];
#pragma unroll
  for (int i = 0; i < 4; ++i)
#pragma unroll
    for (int j = 0; j < 2; ++j) acc[i][j] = (f32x4){0.f, 0.f, 0.f, 0.f};
  __syncthreads();

  // build-task mapping: wave wv owns rows [wv*8, wv*8+8); lane -> (row, granule)
  const int brow = wv * 8 + (lane >> 3);
  const int gg = lane & 7;
  const float4 pv = ((const float4*)pts_l)[brow];

  // build the entire A image (4 tasks/lane), ONE barrier
#pragma unroll
  for (int cc2 = 0; cc2 < 4; ++cc2) {
    const int chunk = cc2 * 2 + (gg >> 2), g2 = gg & 3;
    build_a_hl(chunk * 32 + g2 * 8, g2, brow, pv, w1_l, b1_l,
               Ahh[chunk], All[chunk]);
  }
  __syncthreads();

  // A fragment addresses (chunk-invariant)
  int ao[4];
#pragma unroll
  for (int mt = 0; mt < 4; ++mt) {
    int m = mt * 16 + c0;
    ao[mt] = m * 32 + ((g ^ ((m >> 1) & 3)) << 3);
  }
  // register double-buffer of A fragments, one chunk ahead
  bf16x8 pah[2][4], pal[2][4];
#pragma unroll
  for (int mt = 0; mt < 4; ++mt) {
    pah[0][mt] = *(const bf16x8*)&Ahh[0][ao[mt]];
    pal[0][mt] = *(const bf16x8*)&All[0][ao[mt]];
  }
#pragma unroll
  for (int c = 0; c < 8; ++c) {
    const int cur = c & 1, nxt = cur ^ 1;
    if (c < 7) {
#pragma unroll
      for (int mt = 0; mt < 4; ++mt) {
        pah[nxt][mt] = *(const bf16x8*)&Ahh[c + 1][ao[mt]];
        pal[nxt][mt] = *(const bf16x8*)&All[c + 1][ao[mt]];
      }
    }
#pragma unroll
    for (int mt = 0; mt < 4; ++mt)
#pragma unroll
      for (int nt = 0; nt < 2; ++nt) {
        acc[mt][nt] = __builtin_amdgcn_mfma_f32_16x16x32_bf16(pah[cur][mt], rbh[c][nt], acc[mt][nt], 0, 0, 0);
        acc[mt][nt] = __builtin_amdgcn_mfma_f32_16x16x32_bf16(pal[cur][mt], rbh[c][nt], acc[mt][nt], 0, 0, 0);
        acc[mt][nt] = __builtin_amdgcn_mfma_f32_16x16x32_bf16(pah[cur][mt], rbl[c][nt], acc[mt][nt], 0, 0, 0);
      }
  }

  // ---- epilogue: s row-sums only ----
  float wsr[2], b2v[2];
#pragma unroll
  for (int nt = 0; nt < 2; ++nt) {
    int col = wv * 32 + nt * 16 + c0;
    wsr[nt] = wsv[col]; b2v[nt] = b2[col];
  }
#pragma unroll
  for (int mt = 0; mt < 4; ++mt) {
    float srow[4] = {0.f, 0.f, 0.f, 0.f};
#pragma unroll
    for (int nt = 0; nt < 2; ++nt) {
      f32x4 z = acc[mt][nt];
#pragma unroll
      for (int r = 0; r < 4; ++r)
        srow[r] = fmaf(fmaxf(z[r] + b2v[nt], 0.f), wsr[nt], srow[r]);
    }
#pragma unroll
    for (int r = 0; r < 4; ++r) {
#pragma unroll
      for (int off = 1; off <= 8; off <<= 1) srow[r] += __shfl_xor(srow[r], off);
      if (c0 == 0) spart[(mt * 16 + g * 4 + r) * 8 + wv] = srow[r];
    }
  }
  __syncthreads();
  if (t < 64) {
    float s = bs[0];
#pragma unroll
    for (int w8 = 0; w8 < 8; ++w8) s += spart[t * 8 + w8];
    s_raw[m0 + t] = s;
    float s2 = s * s;
#pragma unroll
    for (int off = 32; off >= 1; off >>= 1) {
      s += __shfl_down(s, off);
      s2 += __shfl_down(s2, off);
    }
    if (t == 0) {
      atomicAdd(&stats_f[SI_SUMS], s);
      atomicAdd(&stats_f[SI_SUMS2], s2);
    }
  }
}

// ---------------- K2: fused scores + LDS hist + scan + scatter + rank ----------------
// Linear monotone bucketing (sc*BSCALE) spreads the plateau-clustered scores
// over thousands of buckets: ~10x less LDS-atomic contention, short segments.
__global__ __launch_bounds__(1024) void k_sel(
    const float* __restrict__ s_raw, float* stats_f,
    const float* __restrict__ gamma, const float* __restrict__ beta,
    unsigned* __restrict__ suf_g, ull* __restrict__ cand,
    int* __restrict__ flat_idx, float* __restrict__ sw_raw)
{
  __shared__ __align__(16) unsigned lh[NBUCK];      // 64 KB
  __shared__ unsigned wsum[16], wsuf[16];
  __shared__ unsigned sb_cut, sb_tot;
  __shared__ float esel_sh[16];
  const int batch = blockIdx.x, t = threadIdx.x;
  const int lane = t & 63, w = t >> 6;
  const float mu = stats_f[SI_SUMS] * (1.f / 65536.f);
  const float ex2 = stats_f[SI_SUMS2] * (1.f / 65536.f);
  const float istd = 1.f / sqrtf(ex2 - mu * mu + 1e-5f);
  const float gm = gamma[0], be = beta[0];
  if (t == 0) { sb_cut = 0u; sb_tot = PPB; }
#pragma unroll
  for (int j = 0; j < 16; ++j) lh[j * 1024 + t] = 0u;
  __syncthreads();
  float sc_loc[16];
#pragma unroll
  for (int j = 0; j < 16; ++j) {
    float sc = fmaxf((s_raw[batch * PPB + j * 1024 + t] - mu) * istd * gm + be, 0.f);
    sc_loc[j] = sc;
    unsigned bucket = sc2bucket(sc);
    if (bucket >= 1u) atomicAdd(&lh[bucket], 1u);
  }
  __syncthreads();
  unsigned hl[16]; unsigned ct = 0;
#pragma unroll
  for (int i = 0; i < 16; ++i) { hl[i] = lh[t * 16 + i]; ct += hl[i]; }
  unsigned x = ct;
#pragma unroll
  for (int off = 1; off <= 32; off <<= 1) {
    unsigned v = __shfl_down(x, off);
    if (lane + off < 64) x += v;
  }
  if (lane == 0) wsum[w] = x;
  __syncthreads();
  if (t < 16) {
    unsigned s = 0;
    for (int j = t + 1; j < 16; ++j) s += wsum[j];
    wsuf[t] = s;
  }
  __syncthreads();
  unsigned run = wsuf[w] + (x - ct);
  for (int i = 15; i >= 0; --i) {
    int b = t * 16 + i;
    unsigned h = hl[i];
    lh[b] = run;
    if (b >= 1 && run < TOPK && run + h >= TOPK) { sb_cut = (unsigned)b; sb_tot = run + h; }
    run += h;
  }
  if (t == 0 && run < TOPK) { sb_cut = 0u; sb_tot = PPB; }
  __syncthreads();
#pragma unroll
  for (int j = 0; j < 16; ++j) suf_g[batch * NBUCK + j * 1024 + t] = lh[j * 1024 + t];
  __syncthreads();
  const unsigned cut = sb_cut, tot = sb_tot;
#pragma unroll
  for (int j = 0; j < 16; ++j) {
    float sc = sc_loc[j];
    unsigned bucket = sc2bucket(sc);
    if (bucket >= cut) {
      unsigned pos = atomicAdd(&lh[bucket], 1u);
      cand[batch * PPB + pos] =
          ((ull)__float_as_uint(sc) << 32) | (ull)(~(unsigned)(batch * PPB + j * 1024 + t));
    }
  }
  __threadfence();
  __syncthreads();
  // cursors dead now — reuse lh's 64 KB as ull candidate cache for the rank scan
  ull* cl = (ull*)lh;
  const bool use_lds = (tot <= 8192u);
  if (use_lds)
    for (unsigned pos = t; pos < tot; pos += 1024) cl[pos] = cand[batch * PPB + pos];
  __syncthreads();
  const ull* seg = use_lds ? (const ull*)cl : &cand[batch * PPB];
  float esel = 0.f;
  for (int pos = t; pos < (int)tot; pos += 1024) {
    ull key = seg[pos];
    unsigned bits = (unsigned)(key >> 32);
    unsigned bucket = sc2bucket(__uint_as_float(bits));
    unsigned s0 = suf_g[batch * NBUCK + bucket];
    unsigned s1 = (bucket >= 1u) ? suf_g[batch * NBUCK + bucket - 1] : tot;
    unsigned rank = s0;
    for (unsigned p = s0; p < s1; ++p) rank += (seg[p] > key);
    if (rank < TOPK) {
      float E = expf((__uint_as_float(bits) - 5.f) * 10.f);
      flat_idx[batch * TOPK + rank] = (int)(~(unsigned)key);
      sw_raw[batch * TOPK + rank] = E;
      esel += E;
    }
  }
#pragma unroll
  for (int off = 32; off >= 1; off >>= 1) esel += __shfl_down(esel, off);
  if (lane == 0) esel_sh[w] = esel;
  __syncthreads();
  if (t == 0) {
    float s = 0.f;
    for (int j = 0; j < 16; ++j) s += esel_sh[j];
    stats_f[SI_ESEL + batch] = s;
  }
}

// ---------------- K3: fused double-GEMM processor, M=64/block, 8 waves ----------------
// v5: both GEMMs run with zero in-loop VMEM: GEMM1's B slice preloaded to
// registers up front (latency under staging+build+barrier), GEMM2's B slice
// preloaded during the sf transform + barrier. A register-double-buffered.
__global__ __launch_bounds__(512, 2) void k_proc(
    const float4* __restrict__ pts4, const float* __restrict__ w1,
    const float* __restrict__ b1,
    const unsigned short* __restrict__ w2h, const unsigned short* __restrict__ w2l,
    const float* __restrict__ b2,
    const float* stats_f, const int* __restrict__ flat_idx,
    const float* __restrict__ sw_raw,
    const unsigned short* __restrict__ p1h, const unsigned short* __restrict__ p1l,
    const float* __restrict__ bp1,
    const float4* __restrict__ wp2_4, const float* __restrict__ bp2,
    float4* __restrict__ out4)
{
  __shared__ float w1_l[1024];
  __shared__ float b1_l[256];
  __shared__ int idx_t[64];
  __shared__ float sw_t[64];
  __shared__ __align__(16) short sf_s[16384];   // 32 KB: 8 slabs [64 x 32k] swizzled
  __shared__ __align__(16) short Ah1[8][2048];  // 32 KB: GEMM1 A image, all chunks
  __shared__ float4 opart[512];                 // 8 KB: 64 rows x 8 waves

  const int t = threadIdx.x;
  const int m0 = blockIdx.x * 64;
  const int b = m0 >> 12;
  const int wv = t >> 6, lane = t & 63, g = lane >> 4, c0 = lane & 15;

  int boff[2];
#pragma unroll
  for (int nt = 0; nt < 2; ++nt) {
    int n = wv * 32 + nt * 16 + c0;
    boff[nt] = n * 32 + ((g ^ ((n >> 1) & 3)) << 3);
  }

  // GEMM1 B slice -> registers, up front
  bf16x8 rbh[8][2], rbl[8][2];
#pragma unroll
  for (int c = 0; c < 8; ++c)
#pragma unroll
    for (int nt = 0; nt < 2; ++nt) {
      rbh[c][nt] = *(const bf16x8*)&w2h[c * 8192 + boff[nt]];
      rbl[c][nt] = *(const bf16x8*)&w2l[c * 8192 + boff[nt]];
    }

#pragma unroll
  for (int i = 0; i < 2; ++i) w1_l[i * 512 + t] = w1[i * 512 + t];
  if (t < 256) b1_l[t] = b1[t];
  if (t < 64) {
    idx_t[t] = flat_idx[m0 + t];
    sw_t[t] = sw_raw[m0 + t] / stats_f[SI_ESEL + b];
  }
  f32x4 acc[4][2];
#pragma unroll
  for (int i = 0; i < 4; ++i)
#pragma unroll
    for (int j = 0; j < 2; ++j) acc[i][j] = (f32x4){0.f, 0.f, 0.f, 0.f};
  __syncthreads();

  const int brow = wv * 8 + (lane >> 3);
  const int gg = lane & 7;
  const float4 pv = pts4[idx_t[brow]];
  float swr[4][4];
#pragma unroll
  for (int mt = 0; mt < 4; ++mt)
#pragma unroll
    for (int r = 0; r < 4; ++r) swr[mt][r] = sw_t[mt * 16 + g * 4 + r];

  // ===== GEMM1: z1 = h @ w2 (A = RTNE bf16 of h via LDS; B = w2 hi/lo 2-chain) =====
#pragma unroll
  for (int cc2 = 0; cc2 < 4; ++cc2) {
    const int chunk = cc2 * 2 + (gg >> 2), g2 = gg & 3;
    build_a_h(chunk * 32 + g2 * 8, g2, brow, pv, w1_l, b1_l, Ah1[chunk]);
  }
  __syncthreads();

  int ao[4];
#pragma unroll
  for (int mt = 0; mt < 4; ++mt) {
    int m = mt * 16 + c0;
    ao[mt] = m * 32 + ((g ^ ((m >> 1) & 3)) << 3);
  }
  bf16x8 paf[2][4];
#pragma unroll
  for (int mt = 0; mt < 4; ++mt) paf[0][mt] = *(const bf16x8*)&Ah1[0][ao[mt]];
#pragma unroll
  for (int c = 0; c < 8; ++c) {
    const int cur = c & 1, nxt = cur ^ 1;
    if (c < 7) {
#pragma unroll
      for (int mt = 0; mt < 4; ++mt)
        paf[nxt][mt] = *(const bf16x8*)&Ah1[c + 1][ao[mt]];
    }
#pragma unroll
    for (int mt = 0; mt < 4; ++mt)
#pragma unroll
      for (int nt = 0; nt < 2; ++nt) {
        acc[mt][nt] = __builtin_amdgcn_mfma_f32_16x16x32_bf16(paf[cur][mt], rbh[c][nt], acc[mt][nt], 0, 0, 0);
        acc[mt][nt] = __builtin_amdgcn_mfma_f32_16x16x32_bf16(paf[cur][mt], rbl[c][nt], acc[mt][nt], 0, 0, 0);
      }
  }

  // GEMM2 B slice -> registers (latency hidden under transform + barrier)
#pragma unroll
  for (int c = 0; c < 8; ++c)
#pragma unroll
    for (int nt = 0; nt < 2; ++nt) {
      rbh[c][nt] = *(const bf16x8*)&p1h[c * 8192 + boff[nt]];
      rbl[c][nt] = *(const bf16x8*)&p1l[c * 8192 + boff[nt]];
    }

  // ===== transform: sf = relu(z1 + b2) * sw  ->  LDS bf16, A-layout swizzle =====
  {
    float b2v[2];
#pragma unroll
    for (int nt = 0; nt < 2; ++nt) b2v[nt] = b2[wv * 32 + nt * 16 + c0];
#pragma unroll
    for (int mt = 0; mt < 4; ++mt)
#pragma unroll
      for (int nt = 0; nt < 2; ++nt) {
        int n = wv * 32 + nt * 16 + c0;
        int slab = n >> 5, qc = (n >> 3) & 3, kof = n & 7;
#pragma unroll
        for (int r = 0; r < 4; ++r) {
          int m = mt * 16 + g * 4 + r;
          float v = fmaxf(acc[mt][nt][r] + b2v[nt], 0.f) * swr[mt][r];
          sf_s[slab * 2048 + m * 32 + ((qc ^ ((m >> 1) & 3)) << 3) + kof] = f2bf(v);
        }
      }
  }
  __syncthreads();

  // ===== GEMM2: y = sf @ wp1 (A = sf bf16; B = wp1 hi/lo 2-chain) =====
#pragma unroll
  for (int i = 0; i < 4; ++i)
#pragma unroll
    for (int j = 0; j < 2; ++j) acc[i][j] = (f32x4){0.f, 0.f, 0.f, 0.f};
#pragma unroll
  for (int mt = 0; mt < 4; ++mt) paf[0][mt] = *(const bf16x8*)&sf_s[0 * 2048 + ao[mt]];
#pragma unroll
  for (int c = 0; c < 8; ++c) {
    const int cur = c & 1, nxt = cur ^ 1;
    if (c < 7) {
#pragma unroll
      for (int mt = 0; mt < 4; ++mt)
        paf[nxt][mt] = *(const bf16x8*)&sf_s[(c + 1) * 2048 + ao[mt]];
    }
#pragma unroll
    for (int mt = 0; mt < 4; ++mt)
#pragma unroll
      for (int nt = 0; nt < 2; ++nt) {
        acc[mt][nt] = __builtin_amdgcn_mfma_f32_16x16x32_bf16(paf[cur][mt], rbh[c][nt], acc[mt][nt], 0, 0, 0);
        acc[mt][nt] = __builtin_amdgcn_mfma_f32_16x16x32_bf16(paf[cur][mt], rbl[c][nt], acc[mt][nt], 0, 0, 0);
      }
  }

  // ===== epilogue: out = relu(y + bp1) @ wp2 + bp2 (sw already applied) =====
  float4 wq[2]; float bp1v[2];
#pragma unroll
  for (int nt = 0; nt < 2; ++nt) {
    int n = wv * 32 + nt * 16 + c0;
    wq[nt] = wp2_4[n]; bp1v[nt] = bp1[n];
  }
#pragma unroll
  for (int mt = 0; mt < 4; ++mt) {
#pragma unroll
    for (int r = 0; r < 4; ++r) {
      float4 o = {0.f, 0.f, 0.f, 0.f};
#pragma unroll
      for (int nt = 0; nt < 2; ++nt) {
        float y = fmaxf(acc[mt][nt][r] + bp1v[nt], 0.f);
        o.x = fmaf(y, wq[nt].x, o.x); o.y = fmaf(y, wq[nt].y, o.y);
        o.z = fmaf(y, wq[nt].z, o.z); o.w = fmaf(y, wq[nt].w, o.w);
      }
#pragma unroll
      for (int off = 1; off <= 8; off <<= 1) {
        o.x += __shfl_xor(o.x, off); o.y += __shfl_xor(o.y, off);
        o.z += __shfl_xor(o.z, off); o.w += __shfl_xor(o.w, off);
      }
      if (c0 == 0) opart[(mt * 16 + g * 4 + r) * 8 + wv] = o;
    }
  }
  __syncthreads();
  if (t < 64) {
    float4 bp2v = *(const float4*)bp2;
    float4 r = bp2v;
#pragma unroll
    for (int w8 = 0; w8 < 8; ++w8) {
      float4 p = opart[t * 8 + w8];
      r.x += p.x; r.y += p.y; r.z += p.z; r.w += p.w;
    }
    out4[m0 + t] = r;
  }
}

extern "C" void kernel_launch(void* const* d_in, const int* in_sizes, int n_in,
                              void* d_out, int out_size, void* d_ws, size_t ws_size,
                              hipStream_t stream) {
  const float* pts   = (const float*)d_in[0];
  const float* w1    = (const float*)d_in[1];
  const float* b1    = (const float*)d_in[2];
  const float* w2    = (const float*)d_in[3];
  const float* b2    = (const float*)d_in[4];
  const float* wsv   = (const float*)d_in[5];
  const float* bs    = (const float*)d_in[6];
  const float* gamma = (const float*)d_in[7];
  const float* beta  = (const float*)d_in[8];
  const float* wp1   = (const float*)d_in[9];
  const float* bp1   = (const float*)d_in[10];
  const float* wp2   = (const float*)d_in[11];
  const float* bp2   = (const float*)d_in[12];

  char* wsb = (char*)d_ws;
  float*    s_raw   = (float*)(wsb + SRAW_OFF);
  float*    stats_f = (float*)(wsb + ST_OFF);
  unsigned* suf     = (unsigned*)(wsb + SUF_OFF);
  ull*      cand    = (ull*)(wsb + CAND_OFF);
  int*      flat_i  = (int*)(wsb + FIDX_OFF);
  float*    sw_raw  = (float*)(wsb + SW_OFF);
  unsigned short* w2h = (unsigned short*)(wsb + W2SH_OFF);
  unsigned short* w2l = (unsigned short*)(wsb + W2SL_OFF);
  unsigned short* p1h = (unsigned short*)(wsb + WP1H_OFF);
  unsigned short* p1l = (unsigned short*)(wsb + WP1L_OFF);

  hipLaunchKernelGGL(k_prep, dim3(17), dim3(256), 0, stream,
                     w2, wp1, w2h, w2l, p1h, p1l, stats_f);
  hipLaunchKernelGGL(k_mlp, dim3(1024), dim3(512), 0, stream,
                     (const float4*)pts, w1, b1, w2h, w2l, b2, wsv, bs,
                     s_raw, stats_f);
  hipLaunchKernelGGL(k_sel, dim3(NB), dim3(1024), 0, stream,
                     s_raw, stats_f, gamma, beta, suf, cand, flat_i, sw_raw);
  hipLaunchKernelGGL(k_proc, dim3(256), dim3(512), 0, stream,
                     (const float4*)pts, w1, b1, w2h, w2l, b2,
                     stats_f, flat_i, sw_raw, p1h, p1l, bp1,
                     (const float4*)wp2, bp2, (float4*)d_out);
}

// Round 5
// 168.248 us; speedup vs baseline: 1.0689x; 1.0689x over previous
//
#include <hip/hip_runtime.h>
#include <math.h>

typedef unsigned long long ull;
typedef __attribute__((ext_vector_type(8))) short bf16x8;
typedef __attribute__((ext_vector_type(4))) float f32x4;

#define PPB   16384
#define NB    4
#define TOPK  4096
#define NPTS  65536
#define NBUCK 16384
#define BSCALE 2048.0f   // linear monotone bucketing: ~1-3 pts/bucket (scores plateau near max)

// workspace layout (bytes)
#define SRAW_OFF  0u          // N f32 (256 KB)
#define ST_OFF    262144u     // 64 words stats
#define SUF_OFF   262400u     // 4*16384 u32 (256 KB)
#define CAND_OFF  524544u     // 4*16384 u64 (512 KB)
#define FIDX_OFF  1048832u    // 16384 i32
#define SW_OFF    1114368u    // 16384 f32
#define W2SH_OFF  1179904u    // 256*256 bf16 chunk-swizzled image (hi)
#define W2SL_OFF  1310976u    // (lo)
#define WP1H_OFF  1442048u    // wp1^T image (hi)
#define WP1L_OFF  1573120u    // (lo)   end 1704192
#define CURS_OFF  1704192u    // 4*16384 u32 hist/cursors (256 KB) end 1966336

// stats word indices
#define SI_SUMS  0
#define SI_SUMS2 1
#define SI_ESEL  12  // ..15 per-batch sum exp (selected)
#define SI_CUTW  16  // ..19 per-batch cut bucket (u32 bitcast)
#define SI_TOTW  20  // ..23 per-batch candidate count (u32 bitcast)

union frag_u { unsigned d[4]; bf16x8 v; uint4 q; };

__device__ __forceinline__ unsigned short f2bf(float f) {
  unsigned u = __float_as_uint(f);
  unsigned r = 0x7FFFu + ((u >> 16) & 1u);   // RTNE
  return (unsigned short)((u + r) >> 16);
}
__device__ __forceinline__ float bf2f(unsigned short h) {
  return __uint_as_float((unsigned)h << 16);
}
__device__ __forceinline__ unsigned sc2bucket(float sc) {
  unsigned b = (unsigned)(sc * BSCALE);      // monotone in sc (sc >= 0)
  return b > NBUCK - 1u ? NBUCK - 1u : b;
}

// ---- cooperative A-fragment builders (unchanged arithmetic) ----
__device__ __forceinline__ void build_a_hl(
    int kb, int g2, int row, float4 pv,
    const float* __restrict__ w1_l, const float* __restrict__ b1_l,
    short* dh, short* dl)
{
  float wk0[8], wk1[8], wk2[8], wk3[8], bk[8];
  *(float4*)&wk0[0] = *(const float4*)&w1_l[kb];
  *(float4*)&wk0[4] = *(const float4*)&w1_l[kb + 4];
  *(float4*)&wk1[0] = *(const float4*)&w1_l[256 + kb];
  *(float4*)&wk1[4] = *(const float4*)&w1_l[256 + kb + 4];
  *(float4*)&wk2[0] = *(const float4*)&w1_l[512 + kb];
  *(float4*)&wk2[4] = *(const float4*)&w1_l[512 + kb + 4];
  *(float4*)&wk3[0] = *(const float4*)&w1_l[768 + kb];
  *(float4*)&wk3[4] = *(const float4*)&w1_l[768 + kb + 4];
  *(float4*)&bk[0] = *(const float4*)&b1_l[kb];
  *(float4*)&bk[4] = *(const float4*)&b1_l[kb + 4];
  frag_u uh, ul;
#pragma unroll
  for (int jp = 0; jp < 4; ++jp) {
    int j0 = 2 * jp, j1 = 2 * jp + 1;
    float h0 = fmaf(pv.w, wk3[j0], fmaf(pv.z, wk2[j0],
               fmaf(pv.y, wk1[j0], fmaf(pv.x, wk0[j0], bk[j0]))));
    float h1 = fmaf(pv.w, wk3[j1], fmaf(pv.z, wk2[j1],
               fmaf(pv.y, wk1[j1], fmaf(pv.x, wk0[j1], bk[j1]))));
    h0 = fmaxf(h0, 0.f); h1 = fmaxf(h1, 0.f);
    unsigned u0 = __float_as_uint(h0), u1 = __float_as_uint(h1);
    uh.d[jp] = (u0 >> 16) | (u1 & 0xFFFF0000u);
    float r0 = h0 - __uint_as_float(u0 & 0xFFFF0000u);
    float r1 = h1 - __uint_as_float(u1 & 0xFFFF0000u);
    ul.d[jp] = (__float_as_uint(r0) >> 16) | (__float_as_uint(r1) & 0xFFFF0000u);
  }
  const int wo = row * 32 + ((g2 ^ ((row >> 1) & 3)) << 3);
  *(uint4*)&dh[wo] = uh.q;
  *(uint4*)&dl[wo] = ul.q;
}

__device__ __forceinline__ void build_a_h(
    int kb, int g2, int row, float4 pv,
    const float* __restrict__ w1_l, const float* __restrict__ b1_l,
    short* dh)
{
  float wk0[8], wk1[8], wk2[8], wk3[8], bk[8];
  *(float4*)&wk0[0] = *(const float4*)&w1_l[kb];
  *(float4*)&wk0[4] = *(const float4*)&w1_l[kb + 4];
  *(float4*)&wk1[0] = *(const float4*)&w1_l[256 + kb];
  *(float4*)&wk1[4] = *(const float4*)&w1_l[256 + kb + 4];
  *(float4*)&wk2[0] = *(const float4*)&w1_l[512 + kb];
  *(float4*)&wk2[4] = *(const float4*)&w1_l[512 + kb + 4];
  *(float4*)&wk3[0] = *(const float4*)&w1_l[768 + kb];
  *(float4*)&wk3[4] = *(const float4*)&w1_l[768 + kb + 4];
  *(float4*)&bk[0] = *(const float4*)&b1_l[kb];
  *(float4*)&bk[4] = *(const float4*)&b1_l[kb + 4];
  frag_u uh;
#pragma unroll
  for (int jp = 0; jp < 4; ++jp) {
    int j0 = 2 * jp, j1 = 2 * jp + 1;
    float h0 = fmaf(pv.w, wk3[j0], fmaf(pv.z, wk2[j0],
               fmaf(pv.y, wk1[j0], fmaf(pv.x, wk0[j0], bk[j0]))));
    float h1 = fmaf(pv.w, wk3[j1], fmaf(pv.z, wk2[j1],
               fmaf(pv.y, wk1[j1], fmaf(pv.x, wk0[j1], bk[j1]))));
    uh.d[jp] = (unsigned)f2bf(fmaxf(h0, 0.f)) |
               ((unsigned)f2bf(fmaxf(h1, 0.f)) << 16);
  }
  const int wo = row * 32 + ((g2 ^ ((row >> 1) & 3)) << 3);
  *(uint4*)&dh[wo] = uh.q;
}

// ---------------- prep: images (coalesced) + stats/cursor zeroing ----------------
__global__ __launch_bounds__(256) void k_prep(
    const float* __restrict__ w2, const float* __restrict__ wp1,
    unsigned short* __restrict__ w2h, unsigned short* __restrict__ w2l,
    unsigned short* __restrict__ p1h, unsigned short* __restrict__ p1l,
    float* __restrict__ stats, unsigned* __restrict__ curs)
{
  const int t = threadIdx.x, bx = blockIdx.x;
  if (bx == 16) {
    if (t < 64) stats[t] = 0.f;
    return;
  }
  if (bx >= 17) {                 // blocks 17..80 zero the hist/cursor array
    const int bz = bx - 17;       // 64 blocks x 256 thr x 4 words = 64K words
#pragma unroll
    for (int j = 0; j < 4; ++j) curs[bz * 1024 + j * 256 + t] = 0u;
    return;
  }
  __shared__ unsigned short lh[8192], ll[8192];
  const int c = bx & 7;
  const float* src = (bx >= 8) ? wp1 : w2;
  unsigned short* dh = (bx >= 8) ? p1h : w2h;
  unsigned short* dl = (bx >= 8) ? p1l : w2l;
  const int sw = (t >> 1) & 3;
#pragma unroll
  for (int kk = 0; kk < 32; ++kk) {
    float v = src[(c * 32 + kk) * 256 + t];      // coalesced 256-wide
    unsigned short h = f2bf(v);
    int q = kk >> 3, kof = kk & 7;
    int off = t * 32 + ((q ^ sw) << 3) + kof;
    lh[off] = h;
    ll[off] = f2bf(v - bf2f(h));
  }
  __syncthreads();
#pragma unroll
  for (int u = 0; u < 4; ++u) {
    ((uint4*)&dh[c * 8192])[u * 256 + t] = ((const uint4*)lh)[u * 256 + t];
    ((uint4*)&dl[c * 8192])[u * 256 + t] = ((const uint4*)ll)[u * 256 + t];
  }
}

// ---------------- K1: score-only point MLP (round-3 v4, best measured 46.0us) ----------------
__global__ __launch_bounds__(512, 4) void k_mlp(
    const float4* __restrict__ pts4, const float* __restrict__ w1,
    const float* __restrict__ b1,
    const unsigned short* __restrict__ w2h, const unsigned short* __restrict__ w2l,
    const float* __restrict__ b2, const float* __restrict__ wsv,
    const float* __restrict__ bs,
    float* __restrict__ s_raw, float* stats_f)
{
  __shared__ float w1_l[1024];
  __shared__ float b1_l[256];
  __shared__ float pts_l[256];
  __shared__ float spart[512];                   // 64 rows x 8 waves
  __shared__ __align__(16) short Ahh[8][2048];   // 32 KB: A hi, full 64x256 swizzled
  __shared__ __align__(16) short All[8][2048];   // 32 KB: A lo

  const int t = threadIdx.x;
  const int m0 = blockIdx.x * 64;
  const int wv = t >> 6, lane = t & 63, g = lane >> 4, c0 = lane & 15;

#pragma unroll
  for (int i = 0; i < 2; ++i) w1_l[i * 512 + t] = w1[i * 512 + t];
  if (t < 256) b1_l[t] = b1[t];
  if (t < 64) ((float4*)pts_l)[t] = pts4[m0 + t];

  f32x4 acc[4][2];
#pragma unroll
  for (int i = 0; i < 4; ++i)
#pragma unroll
    for (int j = 0; j < 2; ++j) acc[i][j] = (f32x4){0.f, 0.f, 0.f, 0.f};
  __syncthreads();

  const int brow = wv * 8 + (lane >> 3);
  const int gg = lane & 7;
  const float4 pv = ((const float4*)pts_l)[brow];

  int boff[2];
#pragma unroll
  for (int nt = 0; nt < 2; ++nt) {
    int n = wv * 32 + nt * 16 + c0;
    boff[nt] = n * 32 + ((g ^ ((n >> 1) & 3)) << 3);
  }

  bf16x8 bhb[2][2], blb[2][2];
#pragma unroll
  for (int nt = 0; nt < 2; ++nt) {
    bhb[0][nt] = *(const bf16x8*)&w2h[boff[nt]];
    blb[0][nt] = *(const bf16x8*)&w2l[boff[nt]];
  }

#pragma unroll
  for (int cc2 = 0; cc2 < 4; ++cc2) {
    const int chunk = cc2 * 2 + (gg >> 2), g2 = gg & 3;
    build_a_hl(chunk * 32 + g2 * 8, g2, brow, pv, w1_l, b1_l,
               Ahh[chunk], All[chunk]);
  }
  __syncthreads();

#pragma unroll
  for (int c = 0; c < 8; ++c) {
    const int cur = c & 1, nxt = cur ^ 1;
    if (c < 7) {
#pragma unroll
      for (int nt = 0; nt < 2; ++nt) {
        bhb[nxt][nt] = *(const bf16x8*)&w2h[(c + 1) * 8192 + boff[nt]];
        blb[nxt][nt] = *(const bf16x8*)&w2l[(c + 1) * 8192 + boff[nt]];
      }
    }
    bf16x8 ah[4], al[4];
#pragma unroll
    for (int mt = 0; mt < 4; ++mt) {
      int m = mt * 16 + c0;
      int ao = m * 32 + ((g ^ ((m >> 1) & 3)) << 3);
      ah[mt] = *(const bf16x8*)&Ahh[c][ao];
      al[mt] = *(const bf16x8*)&All[c][ao];
    }
#pragma unroll
    for (int mt = 0; mt < 4; ++mt)
#pragma unroll
      for (int nt = 0; nt < 2; ++nt) {
        acc[mt][nt] = __builtin_amdgcn_mfma_f32_16x16x32_bf16(ah[mt], bhb[cur][nt], acc[mt][nt], 0, 0, 0);
        acc[mt][nt] = __builtin_amdgcn_mfma_f32_16x16x32_bf16(al[mt], bhb[cur][nt], acc[mt][nt], 0, 0, 0);
        acc[mt][nt] = __builtin_amdgcn_mfma_f32_16x16x32_bf16(ah[mt], blb[cur][nt], acc[mt][nt], 0, 0, 0);
      }
  }

  float wsr[2], b2v[2];
#pragma unroll
  for (int nt = 0; nt < 2; ++nt) {
    int col = wv * 32 + nt * 16 + c0;
    wsr[nt] = wsv[col]; b2v[nt] = b2[col];
  }
#pragma unroll
  for (int mt = 0; mt < 4; ++mt) {
    float srow[4] = {0.f, 0.f, 0.f, 0.f};
#pragma unroll
    for (int nt = 0; nt < 2; ++nt) {
      f32x4 z = acc[mt][nt];
#pragma unroll
      for (int r = 0; r < 4; ++r)
        srow[r] = fmaf(fmaxf(z[r] + b2v[nt], 0.f), wsr[nt], srow[r]);
    }
#pragma unroll
    for (int r = 0; r < 4; ++r) {
#pragma unroll
      for (int off = 1; off <= 8; off <<= 1) srow[r] += __shfl_xor(srow[r], off);
      if (c0 == 0) spart[(mt * 16 + g * 4 + r) * 8 + wv] = srow[r];
    }
  }
  __syncthreads();
  if (t < 64) {
    float s = bs[0];
#pragma unroll
    for (int w8 = 0; w8 < 8; ++w8) s += spart[t * 8 + w8];
    s_raw[m0 + t] = s;
    float s2 = s * s;
#pragma unroll
    for (int off = 32; off >= 1; off >>= 1) {
      s += __shfl_down(s, off);
      s2 += __shfl_down(s2, off);
    }
    if (t == 0) {
      atomicAdd(&stats_f[SI_SUMS], s);
      atomicAdd(&stats_f[SI_SUMS2], s2);
    }
  }
}

// ---------------- selection, phase A: parallel histogram (64 blocks) ----------------
__global__ __launch_bounds__(1024) void k_selA(
    const float* __restrict__ s_raw, const float* __restrict__ stats_f,
    const float* __restrict__ gamma, const float* __restrict__ beta,
    unsigned* __restrict__ curs)
{
  __shared__ unsigned lh[NBUCK];                 // 64 KB local hist
  const int bx = blockIdx.x, t = threadIdx.x;
  const int batch = bx >> 4, blk = bx & 15;
  const float mu = stats_f[SI_SUMS] * (1.f / 65536.f);
  const float ex2 = stats_f[SI_SUMS2] * (1.f / 65536.f);
  const float istd = 1.f / sqrtf(ex2 - mu * mu + 1e-5f);
  const float gm = gamma[0], be = beta[0];
#pragma unroll
  for (int j = 0; j < 16; ++j) lh[j * 1024 + t] = 0u;
  __syncthreads();
  float sc = fmaxf((s_raw[batch * PPB + blk * 1024 + t] - mu) * istd * gm + be, 0.f);
  unsigned bucket = sc2bucket(sc);
  if (bucket >= 1u) atomicAdd(&lh[bucket], 1u);
  __syncthreads();
#pragma unroll
  for (int j = 0; j < 16; ++j) {
    unsigned v = lh[j * 1024 + t];
    if (v) atomicAdd(&curs[batch * NBUCK + j * 1024 + t], v);
  }
}

// ---------------- selection, phase B: suffix scan + cut (4 blocks, logic identical) ----------------
__global__ __launch_bounds__(1024) void k_selB(
    unsigned* __restrict__ curs, unsigned* __restrict__ suf_g, float* stats_f)
{
  __shared__ unsigned lh[NBUCK];
  __shared__ unsigned wsum[16], wsuf[16];
  __shared__ unsigned sb_cut, sb_tot;
  const int batch = blockIdx.x, t = threadIdx.x;
  const int lane = t & 63, w = t >> 6;
  if (t == 0) { sb_cut = 0u; sb_tot = PPB; }
  unsigned hl[16]; unsigned ct = 0;
#pragma unroll
  for (int i = 0; i < 16; ++i) { hl[i] = curs[batch * NBUCK + t * 16 + i]; ct += hl[i]; }
  unsigned x = ct;
#pragma unroll
  for (int off = 1; off <= 32; off <<= 1) {
    unsigned v = __shfl_down(x, off);
    if (lane + off < 64) x += v;
  }
  if (lane == 0) wsum[w] = x;
  __syncthreads();
  if (t < 16) {
    unsigned s = 0;
    for (int j = t + 1; j < 16; ++j) s += wsum[j];
    wsuf[t] = s;
  }
  __syncthreads();
  unsigned run = wsuf[w] + (x - ct);
  for (int i = 15; i >= 0; --i) {
    int b = t * 16 + i;
    unsigned h = hl[i];
    lh[b] = run;
    if (b >= 1 && run < TOPK && run + h >= TOPK) { sb_cut = (unsigned)b; sb_tot = run + h; }
    run += h;
  }
  if (t == 0 && run < TOPK) { sb_cut = 0u; sb_tot = PPB; }
  __syncthreads();
#pragma unroll
  for (int j = 0; j < 16; ++j) {
    unsigned v = lh[j * 1024 + t];
    suf_g[batch * NBUCK + j * 1024 + t] = v;   // pristine suffix (rank lookups)
    curs[batch * NBUCK + j * 1024 + t] = v;    // mutable cursors (scatter)
  }
  if (t == 0) {
    ((unsigned*)stats_f)[SI_CUTW + batch] = sb_cut;
    ((unsigned*)stats_f)[SI_TOTW + batch] = sb_tot;
  }
}

// ---------------- selection, phase C: parallel scatter (64 blocks) ----------------
__global__ __launch_bounds__(1024) void k_selC(
    const float* __restrict__ s_raw, const float* __restrict__ stats_f,
    const float* __restrict__ gamma, const float* __restrict__ beta,
    unsigned* __restrict__ curs, ull* __restrict__ cand)
{
  const int bx = blockIdx.x, t = threadIdx.x;
  const int batch = bx >> 4, blk = bx & 15;
  const float mu = stats_f[SI_SUMS] * (1.f / 65536.f);
  const float ex2 = stats_f[SI_SUMS2] * (1.f / 65536.f);
  const float istd = 1.f / sqrtf(ex2 - mu * mu + 1e-5f);
  const float gm = gamma[0], be = beta[0];
  const unsigned cut = ((const unsigned*)stats_f)[SI_CUTW + batch];
  const int gi = batch * PPB + blk * 1024 + t;
  float sc = fmaxf((s_raw[gi] - mu) * istd * gm + be, 0.f);   // identical bits to phase A
  unsigned bucket = sc2bucket(sc);
  if (bucket >= cut) {
    unsigned pos = atomicAdd(&curs[batch * NBUCK + bucket], 1u);
    cand[batch * PPB + pos] =
        ((ull)__float_as_uint(sc) << 32) | (ull)(~(unsigned)gi);
  }
}

// ---------------- selection, phase D: parallel rank + outputs (64 blocks) ----------------
__global__ __launch_bounds__(1024) void k_selD(
    const unsigned* __restrict__ suf_g, const ull* __restrict__ cand,
    float* stats_f, int* __restrict__ flat_idx, float* __restrict__ sw_raw)
{
  __shared__ float esel_sh[16];
  const int bx = blockIdx.x, t = threadIdx.x;
  const int batch = bx >> 4, blk = bx & 15;
  const int lane = t & 63, w = t >> 6;
  const unsigned tot = ((const unsigned*)stats_f)[SI_TOTW + batch];
  float esel = 0.f;
  const unsigned pos = (unsigned)(blk * 1024 + t);
  if (pos < tot) {
    const ull* seg = &cand[batch * PPB];
    ull key = seg[pos];
    unsigned bits = (unsigned)(key >> 32);
    unsigned bucket = sc2bucket(__uint_as_float(bits));
    unsigned s0 = suf_g[batch * NBUCK + bucket];
    unsigned s1 = (bucket >= 1u) ? suf_g[batch * NBUCK + bucket - 1] : tot;
    unsigned rank = s0;
    for (unsigned p = s0; p < s1; ++p) rank += (seg[p] > key);
    if (rank < TOPK) {
      float E = expf((__uint_as_float(bits) - 5.f) * 10.f);
      flat_idx[batch * TOPK + rank] = (int)(~(unsigned)key);
      sw_raw[batch * TOPK + rank] = E;
      esel = E;
    }
  }
#pragma unroll
  for (int off = 32; off >= 1; off >>= 1) esel += __shfl_down(esel, off);
  if (lane == 0) esel_sh[w] = esel;
  __syncthreads();
  if (t == 0) {
    float s = 0.f;
#pragma unroll
    for (int j = 0; j < 16; ++j) s += esel_sh[j];
    atomicAdd(&stats_f[SI_ESEL + batch], s);
  }
}

// ---------------- K3: fused double-GEMM processor, M=32/block, grid 512 ----------------
// v6: halve the tile, double the grid -> 2 blocks/CU resident (was exactly 1):
// cross-block overlap covers each block's serial stage->build->GEMM chain.
__global__ __launch_bounds__(512, 4) void k_proc(
    const float4* __restrict__ pts4, const float* __restrict__ w1,
    const float* __restrict__ b1,
    const unsigned short* __restrict__ w2h, const unsigned short* __restrict__ w2l,
    const float* __restrict__ b2,
    const float* stats_f, const int* __restrict__ flat_idx,
    const float* __restrict__ sw_raw,
    const unsigned short* __restrict__ p1h, const unsigned short* __restrict__ p1l,
    const float* __restrict__ bp1,
    const float4* __restrict__ wp2_4, const float* __restrict__ bp2,
    float4* __restrict__ out4)
{
  __shared__ float w1_l[1024];
  __shared__ float b1_l[256];
  __shared__ int idx_t[32];
  __shared__ float sw_t[32];
  __shared__ __align__(16) short sf_s[8192];    // 16 KB: 8 slabs [32 x 32k] swizzled
  __shared__ __align__(16) short Ah1[8][1024];  // 16 KB: GEMM1 A image
  __shared__ float4 opart[256];                 // 4 KB: 32 rows x 8 waves

  const int t = threadIdx.x;
  const int m0 = blockIdx.x * 32;
  const int b = m0 >> 12;
  const int wv = t >> 6, lane = t & 63, g = lane >> 4, c0 = lane & 15;

#pragma unroll
  for (int i = 0; i < 2; ++i) w1_l[i * 512 + t] = w1[i * 512 + t];
  if (t < 256) b1_l[t] = b1[t];
  if (t < 32) {
    idx_t[t] = flat_idx[m0 + t];
    sw_t[t] = sw_raw[m0 + t] / stats_f[SI_ESEL + b];
  }
  f32x4 acc[2][2];
#pragma unroll
  for (int i = 0; i < 2; ++i)
#pragma unroll
    for (int j = 0; j < 2; ++j) acc[i][j] = (f32x4){0.f, 0.f, 0.f, 0.f};
  __syncthreads();

  float swr[2][4];
#pragma unroll
  for (int mt = 0; mt < 2; ++mt)
#pragma unroll
    for (int r = 0; r < 4; ++r) swr[mt][r] = sw_t[mt * 16 + g * 4 + r];

  int boff[2];
#pragma unroll
  for (int nt = 0; nt < 2; ++nt) {
    int n = wv * 32 + nt * 16 + c0;
    boff[nt] = n * 32 + ((g ^ ((n >> 1) & 3)) << 3);
  }

  // ===== GEMM1: z1 = h @ w2 =====
  bf16x8 bhb[2][2], blb[2][2];
#pragma unroll
  for (int nt = 0; nt < 2; ++nt) {
    bhb[0][nt] = *(const bf16x8*)&w2h[boff[nt]];
    blb[0][nt] = *(const bf16x8*)&w2l[boff[nt]];
  }
  // build: 1024 (row, granule) tasks over 512 lanes, 2 each
#pragma unroll
  for (int it = 0; it < 2; ++it) {
    const int tid = it * 512 + t;
    const int row = tid >> 5, gk = tid & 31;
    const int chunk = gk >> 2, g2 = gk & 3;
    const float4 pv = pts4[idx_t[row]];
    build_a_h(chunk * 32 + g2 * 8, g2, row, pv, w1_l, b1_l, Ah1[chunk]);
  }
  __syncthreads();

  int ao[2];
#pragma unroll
  for (int mt = 0; mt < 2; ++mt) {
    int m = mt * 16 + c0;
    ao[mt] = m * 32 + ((g ^ ((m >> 1) & 3)) << 3);
  }
#pragma unroll
  for (int c = 0; c < 8; ++c) {
    const int cur = c & 1, nxt = cur ^ 1;
    if (c < 7) {
#pragma unroll
      for (int nt = 0; nt < 2; ++nt) {
        bhb[nxt][nt] = *(const bf16x8*)&w2h[(c + 1) * 8192 + boff[nt]];
        blb[nxt][nt] = *(const bf16x8*)&w2l[(c + 1) * 8192 + boff[nt]];
      }
    }
    bf16x8 af[2];
#pragma unroll
    for (int mt = 0; mt < 2; ++mt) af[mt] = *(const bf16x8*)&Ah1[c][ao[mt]];
#pragma unroll
    for (int mt = 0; mt < 2; ++mt)
#pragma unroll
      for (int nt = 0; nt < 2; ++nt) {
        acc[mt][nt] = __builtin_amdgcn_mfma_f32_16x16x32_bf16(af[mt], bhb[cur][nt], acc[mt][nt], 0, 0, 0);
        acc[mt][nt] = __builtin_amdgcn_mfma_f32_16x16x32_bf16(af[mt], blb[cur][nt], acc[mt][nt], 0, 0, 0);
      }
  }

  // ===== transform: sf = relu(z1 + b2) * sw -> LDS bf16, A-layout swizzle =====
  {
    float b2v[2];
#pragma unroll
    for (int nt = 0; nt < 2; ++nt) b2v[nt] = b2[wv * 32 + nt * 16 + c0];
#pragma unroll
    for (int mt = 0; mt < 2; ++mt)
#pragma unroll
      for (int nt = 0; nt < 2; ++nt) {
        int n = wv * 32 + nt * 16 + c0;
        int slab = n >> 5, qc = (n >> 3) & 3, kof = n & 7;
#pragma unroll
        for (int r = 0; r < 4; ++r) {
          int m = mt * 16 + g * 4 + r;
          float v = fmaxf(acc[mt][nt][r] + b2v[nt], 0.f) * swr[mt][r];
          sf_s[slab * 1024 + m * 32 + ((qc ^ ((m >> 1) & 3)) << 3) + kof] = f2bf(v);
        }
      }
  }
  __syncthreads();

  // ===== GEMM2: y = sf @ wp1 =====
#pragma unroll
  for (int i = 0; i < 2; ++i)
#pragma unroll
    for (int j = 0; j < 2; ++j) acc[i][j] = (f32x4){0.f, 0.f, 0.f, 0.f};
#pragma unroll
  for (int nt = 0; nt < 2; ++nt) {
    bhb[0][nt] = *(const bf16x8*)&p1h[boff[nt]];
    blb[0][nt] = *(const bf16x8*)&p1l[boff[nt]];
  }
#pragma unroll
  for (int c = 0; c < 8; ++c) {
    const int cur = c & 1, nxt = cur ^ 1;
    if (c < 7) {
#pragma unroll
      for (int nt = 0; nt < 2; ++nt) {
        bhb[nxt][nt] = *(const bf16x8*)&p1h[(c + 1) * 8192 + boff[nt]];
        blb[nxt][nt] = *(const bf16x8*)&p1l[(c + 1) * 8192 + boff[nt]];
      }
    }
    bf16x8 af[2];
#pragma unroll
    for (int mt = 0; mt < 2; ++mt) af[mt] = *(const bf16x8*)&sf_s[c * 1024 + ao[mt]];
#pragma unroll
    for (int mt = 0; mt < 2; ++mt)
#pragma unroll
      for (int nt = 0; nt < 2; ++nt) {
        acc[mt][nt] = __builtin_amdgcn_mfma_f32_16x16x32_bf16(af[mt], bhb[cur][nt], acc[mt][nt], 0, 0, 0);
        acc[mt][nt] = __builtin_amdgcn_mfma_f32_16x16x32_bf16(af[mt], blb[cur][nt], acc[mt][nt], 0, 0, 0);
      }
  }

  // ===== epilogue: out = relu(y + bp1) @ wp2 + bp2 =====
  float4 wq[2]; float bp1v[2];
#pragma unroll
  for (int nt = 0; nt < 2; ++nt) {
    int n = wv * 32 + nt * 16 + c0;
    wq[nt] = wp2_4[n]; bp1v[nt] = bp1[n];
  }
#pragma unroll
  for (int mt = 0; mt < 2; ++mt) {
#pragma unroll
    for (int r = 0; r < 4; ++r) {
      float4 o = {0.f, 0.f, 0.f, 0.f};
#pragma unroll
      for (int nt = 0; nt < 2; ++nt) {
        float y = fmaxf(acc[mt][nt][r] + bp1v[nt], 0.f);
        o.x = fmaf(y, wq[nt].x, o.x); o.y = fmaf(y, wq[nt].y, o.y);
        o.z = fmaf(y, wq[nt].z, o.z); o.w = fmaf(y, wq[nt].w, o.w);
      }
#pragma unroll
      for (int off = 1; off <= 8; off <<= 1) {
        o.x += __shfl_xor(o.x, off); o.y += __shfl_xor(o.y, off);
        o.z += __shfl_xor(o.z, off); o.w += __shfl_xor(o.w, off);
      }
      if (c0 == 0) opart[(mt * 16 + g * 4 + r) * 8 + wv] = o;
    }
  }
  __syncthreads();
  if (t < 32) {
    float4 bp2v = *(const float4*)bp2;
    float4 r = bp2v;
#pragma unroll
    for (int w8 = 0; w8 < 8; ++w8) {
      float4 p = opart[t * 8 + w8];
      r.x += p.x; r.y += p.y; r.z += p.z; r.w += p.w;
    }
    out4[m0 + t] = r;
  }
}

extern "C" void kernel_launch(void* const* d_in, const int* in_sizes, int n_in,
                              void* d_out, int out_size, void* d_ws, size_t ws_size,
                              hipStream_t stream) {
  const float* pts   = (const float*)d_in[0];
  const float* w1    = (const float*)d_in[1];
  const float* b1    = (const float*)d_in[2];
  const float* w2    = (const float*)d_in[3];
  const float* b2    = (const float*)d_in[4];
  const float* wsv   = (const float*)d_in[5];
  const float* bs    = (const float*)d_in[6];
  const float* gamma = (const float*)d_in[7];
  const float* beta  = (const float*)d_in[8];
  const float* wp1   = (const float*)d_in[9];
  const float* bp1   = (const float*)d_in[10];
  const float* wp2   = (const float*)d_in[11];
  const float* bp2   = (const float*)d_in[12];

  char* wsb = (char*)d_ws;
  float*    s_raw   = (float*)(wsb + SRAW_OFF);
  float*    stats_f = (float*)(wsb + ST_OFF);
  unsigned* suf     = (unsigned*)(wsb + SUF_OFF);
  ull*      cand    = (ull*)(wsb + CAND_OFF);
  int*      flat_i  = (int*)(wsb + FIDX_OFF);
  float*    sw_raw  = (float*)(wsb + SW_OFF);
  unsigned short* w2h = (unsigned short*)(wsb + W2SH_OFF);
  unsigned short* w2l = (unsigned short*)(wsb + W2SL_OFF);
  unsigned short* p1h = (unsigned short*)(wsb + WP1H_OFF);
  unsigned short* p1l = (unsigned short*)(wsb + WP1L_OFF);
  unsigned* curs    = (unsigned*)(wsb + CURS_OFF);

  hipLaunchKernelGGL(k_prep, dim3(81), dim3(256), 0, stream,
                     w2, wp1, w2h, w2l, p1h, p1l, stats_f, curs);
  hipLaunchKernelGGL(k_mlp, dim3(1024), dim3(512), 0, stream,
                     (const float4*)pts, w1, b1, w2h, w2l, b2, wsv, bs,
                     s_raw, stats_f);
  hipLaunchKernelGGL(k_selA, dim3(64), dim3(1024), 0, stream,
                     s_raw, stats_f, gamma, beta, curs);
  hipLaunchKernelGGL(k_selB, dim3(NB), dim3(1024), 0, stream,
                     curs, suf, stats_f);
  hipLaunchKernelGGL(k_selC, dim3(64), dim3(1024), 0, stream,
                     s_raw, stats_f, gamma, beta, curs, cand);
  hipLaunchKernelGGL(k_selD, dim3(64), dim3(1024), 0, stream,
                     suf, cand, stats_f, flat_i, sw_raw);
  hipLaunchKernelGGL(k_proc, dim3(512), dim3(512), 0, stream,
                     (const float4*)pts, w1, b1, w2h, w2l, b2,
                     stats_f, flat_i, sw_raw, p1h, p1l, bp1,
                     (const float4*)wp2, bp2, (float4*)d_out);
}